// Round 4
// baseline (563.256 us; speedup 1.0000x reference)
//
#include <hip/hip_runtime.h>
#include <hip/hip_bf16.h>
#include <math.h>

#define D_ 256
#define B_ 65536
#define C_ 1000

typedef _Float16 f16x8 __attribute__((ext_vector_type(8)));
typedef _Float16 f16x4 __attribute__((ext_vector_type(4)));
typedef float f32x4 __attribute__((ext_vector_type(4)));

// ---------------- kernel 0: transpose bc (256x256 f32) + zero loss acc ----------------
__global__ void transpose_kernel(const float* __restrict__ in, float* __restrict__ out,
                                 double* __restrict__ acc) {
  __shared__ float t[32][33];
  if (blockIdx.x == 0 && threadIdx.x == 0) *acc = 0.0;
  const int bx = blockIdx.x & 7, by = blockIdx.x >> 3;
  const int lx = threadIdx.x & 31, ly = threadIdx.x >> 5;  // 32 x 8
#pragma unroll
  for (int s = 0; s < 4; ++s) {
    int r = by * 32 + ly + s * 8;
    t[ly + s * 8][lx] = in[r * 256 + bx * 32 + lx];
  }
  __syncthreads();
#pragma unroll
  for (int s = 0; s < 4; ++s) {
    int r = bx * 32 + ly + s * 8;
    out[r * 256 + by * 32 + lx] = t[lx][ly + s * 8];
  }
}

// ---------------- kernel 1: cov = bc @ bc^T in fp64 (coalesced via bcT) ----------------
__global__ void cov_kernel(const float* __restrict__ bc, const float* __restrict__ bcT,
                           double* __restrict__ C64) {
  const int i = blockIdx.x, j = threadIdx.x;
  __shared__ float ri[D_];
  ri[j] = bc[i * D_ + j];
  __syncthreads();
  double s = 0.0;
#pragma unroll 8
  for (int k = 0; k < D_; ++k) s += (double)ri[k] * (double)bcT[k * D_ + j];
  C64[i * D_ + j] = s;
}

// ---------------- kernel 2a: factor panel p (64 cols), rows in registers ----------------
__global__ __launch_bounds__(256, 1) void chol_panel(double* __restrict__ A, int p) {
  const int j0 = p * 64;
  const int r = threadIdx.x;
  __shared__ double rowv[64];
  __shared__ double dinv;
  double pr[64];
  const bool act = (r >= j0);
  if (act) {
#pragma unroll
    for (int k = 0; k < 64; ++k) pr[k] = A[(size_t)r * D_ + j0 + k];
  }
#pragma unroll
  for (int j = 0; j < 64; ++j) {
    const int col = j0 + j;
    if (r == col) { double d = sqrt(pr[j]); pr[j] = d; dinv = 1.0 / d; }
    __syncthreads();
    if (r > col) {
      double lr = pr[j] * dinv;
      pr[j] = lr;
      if (r < j0 + 64) rowv[r - j0] = lr;
    }
    __syncthreads();
    if (r > col) {
      const double lr = pr[j];
#pragma unroll
      for (int k = j + 1; k < 64; ++k) pr[k] -= lr * rowv[k];
    }
  }
  if (act) {
    const int kmax = (r - j0 < 63) ? (r - j0) : 63;
#pragma unroll
    for (int k = 0; k < 64; ++k)
      if (k <= kmax) A[(size_t)r * D_ + j0 + k] = pr[k];
  }
}

// ---------------- kernel 2b: trailing update for panel p, one block per 64x64 tile ----
__global__ __launch_bounds__(256) void chol_trail(double* __restrict__ A, int p) {
  const int j0 = p * 64;
  const int t0 = j0 + 64;
  int b = blockIdx.x, I = 0;
  while (b >= I + 1) { b -= I + 1; ++I; }   // lower tile pair (I,J), J<=I
  const int J = b;
  const int r0 = t0 + I * 64, c0 = t0 + J * 64;
  __shared__ double LR[64][67];
  __shared__ double LC[64][67];
  const int tid = threadIdx.x;
  for (int e = tid; e < 64 * 64; e += 256) {
    int rr = e >> 6, cc = e & 63;
    LR[rr][cc] = A[(size_t)(r0 + rr) * D_ + j0 + cc];
    LC[rr][cc] = A[(size_t)(c0 + rr) * D_ + j0 + cc];
  }
  __syncthreads();
  const int tx = tid & 15, ty = tid >> 4;
  double acc[4][4];
#pragma unroll
  for (int i = 0; i < 4; ++i)
#pragma unroll
    for (int j = 0; j < 4; ++j) acc[i][j] = 0.0;
#pragma unroll 4
  for (int k = 0; k < 64; ++k) {
    double a_[4], b_[4];
#pragma unroll
    for (int i = 0; i < 4; ++i) a_[i] = LR[ty + 16 * i][k];
#pragma unroll
    for (int j = 0; j < 4; ++j) b_[j] = LC[tx + 16 * j][k];
#pragma unroll
    for (int i = 0; i < 4; ++i)
#pragma unroll
      for (int j = 0; j < 4; ++j) acc[i][j] += a_[i] * b_[j];
  }
#pragma unroll
  for (int i = 0; i < 4; ++i) {
    const int grow = r0 + ty + 16 * i;
#pragma unroll
    for (int j = 0; j < 4; ++j) {
      const int gcol = c0 + tx + 16 * j;
      A[(size_t)grow * D_ + gcol] -= acc[i][j];
    }
  }
}

// ---------------- kernel 3: W = L^-1 column c, chunked forward substitution ----
__global__ __launch_bounds__(256) void inv_kernel(const double* __restrict__ L,
                                                  double* __restrict__ Wcol) {
  const int c = blockIdx.x;
  const int tid = threadIdx.x;
  __shared__ double w[D_];
  __shared__ double rdi[D_];
  __shared__ double rhs[32];
  __shared__ double Ldd[32][33];
  w[tid] = 0.0;
  rdi[tid] = 1.0 / L[(size_t)tid * D_ + tid];
  __syncthreads();
  const int q0 = c >> 5;
  for (int q = q0; q < 8; ++q) {
    const int i0 = q * 32;
    const int ii = tid >> 3, s = tid & 7;
    const int i = i0 + ii;
    double part = 0.0;
    for (int k = c + s; k < i0; k += 8) part += L[(size_t)i * D_ + k] * w[k];
    part += __shfl_xor(part, 1, 64);
    part += __shfl_xor(part, 2, 64);
    part += __shfl_xor(part, 4, 64);
    if (s == 0) rhs[ii] = ((i == c) ? 1.0 : 0.0) - part;
    for (int e = tid; e < 32 * 32; e += 256) {
      int rr = e >> 5, cc = e & 31;
      Ldd[rr][cc] = L[(size_t)(i0 + rr) * D_ + i0 + cc];
    }
    __syncthreads();
    if (tid < 32) {
      double x = rhs[tid];
      double v = 0.0;
      for (int j = 0; j < 32; ++j) {
        double xj = __shfl(x, j, 64);
        double wj = xj * rdi[i0 + j];
        if (tid == j) v = wj;
        if (tid > j) x -= Ldd[tid][j] * wj;
      }
      w[i0 + tid] = v;
      Wcol[(size_t)c * D_ + i0 + tid] = v;   // Wcol[c*D+i] = W[i][c]
    }
    __syncthreads();
  }
}

// ---------------- kernel 4: cast to f16 (block = k, thread = i: coalesced reads) -------
__global__ void convert_kernel(const double* __restrict__ Wcol,
                               _Float16* __restrict__ Wb, _Float16* __restrict__ WbT) {
  int k = blockIdx.x, i = threadIdx.x;
  float v = (k <= i) ? (float)Wcol[k * D_ + i] : 0.0f;
  _Float16 h = (_Float16)v;
  Wb[i * D_ + k] = h;
  WbT[k * D_ + i] = h;
}

// ---------------- kernel 5: signatures, NORMALIZED output, pad rows zeroed -------------
__global__ void sig_kernel(const float* __restrict__ S, const _Float16* __restrict__ WbT,
                           _Float16* __restrict__ sHat) {
  int c = blockIdx.x, i = threadIdx.x;
  if (c >= C_) { sHat[c * D_ + i] = (_Float16)0.0f; return; }  // pad rows exactly 0
  __shared__ float srow[D_];
  __shared__ float wred[4];
  srow[i] = S[c * D_ + i];
  __syncthreads();
  float t = 0.f;
  for (int k = 0; k < D_; ++k) t += (float)WbT[k * D_ + i] * srow[k];
  float ss = t * t;
#pragma unroll
  for (int d = 1; d < 64; d <<= 1) ss += __shfl_xor(ss, d, 64);
  if ((i & 63) == 0) wred[i >> 6] = ss;
  __syncthreads();
  float tot = wred[0] + wred[1] + wred[2] + wred[3];
  float rn = 1.0f / fmaxf(sqrtf(tot), 1e-12f);
  sHat[c * D_ + i] = (_Float16)(t * rn);
}

// ---------------- kernel 6: xHat_un = (X - m) @ W^T (MFMA), rnX per row ----------------
__global__ __launch_bounds__(256) void xform_kernel(const float* __restrict__ X,
                                                    const float* __restrict__ means,
                                                    const _Float16* __restrict__ Wb,
                                                    _Float16* __restrict__ xHat,
                                                    float* __restrict__ rnX) {
  __shared__ __align__(16) _Float16 As[64 * D_];   // 32 KB, swizzled
  __shared__ __align__(16) _Float16 Bs[128 * D_];  // 64 KB, swizzled
  __shared__ float msh[D_];
  const int tid = threadIdx.x;
  const int rowbase = blockIdx.x * 64;
  msh[tid] = means[tid];
  __syncthreads();
  for (int s = 0; s < 16; ++s) {
    int c = s * 256 + tid;
    int r = c >> 6, q = c & 63;
    const float4 xv = *(const float4*)(X + (size_t)(rowbase + r) * D_ + q * 4);
    f16x4 hv;
    hv[0] = (_Float16)(xv.x - msh[q * 4 + 0]);
    hv[1] = (_Float16)(xv.y - msh[q * 4 + 1]);
    hv[2] = (_Float16)(xv.z - msh[q * 4 + 2]);
    hv[3] = (_Float16)(xv.w - msh[q * 4 + 3]);
    int byte = (q * 8) ^ ((r & 7) << 4);
    *(f16x4*)((char*)(As + r * D_) + byte) = hv;
  }
  const int w = tid >> 6, l = tid & 63, lr = l & 15, lq = l >> 4;
  float ss[4] = {0.f, 0.f, 0.f, 0.f};
  for (int ch = 0; ch < 2; ++ch) {
    __syncthreads();
    for (int s = 0; s < 16; ++s) {
      int c = s * 256 + tid;
      int r = c >> 5, q = c & 31;
      uint4 v = *(const uint4*)(Wb + (size_t)(ch * 128 + r) * D_ + q * 8);
      int byte = (q * 16) ^ ((r & 7) << 4);
      *(uint4*)((char*)(Bs + r * D_) + byte) = v;
    }
    __syncthreads();
    f32x4 acc[8];
#pragma unroll
    for (int t = 0; t < 8; ++t) acc[t] = (f32x4){0.f, 0.f, 0.f, 0.f};
#pragma unroll
    for (int ks = 0; ks < 8; ++ks) {
      int arow = w * 16 + lr;
      int abyte = (ks * 64 + lq * 16) ^ ((arow & 7) << 4);
      f16x8 af = *(const f16x8*)((char*)(As + arow * D_) + abyte);
#pragma unroll
      for (int t = 0; t < 8; ++t) {
        int brow = t * 16 + lr;
        int bbyte = (ks * 64 + lq * 16) ^ ((brow & 7) << 4);
        f16x8 bf = *(const f16x8*)((char*)(Bs + brow * D_) + bbyte);
        acc[t] = __builtin_amdgcn_mfma_f32_16x16x32_f16(af, bf, acc[t], 0, 0, 0);
      }
    }
#pragma unroll
    for (int t = 0; t < 8; ++t) {
      int col = ch * 128 + t * 16 + lr;
#pragma unroll
      for (int j = 0; j < 4; ++j) {
        int row = rowbase + w * 16 + lq * 4 + j;
        float v = acc[t][j];
        ss[j] += v * v;
        xHat[(size_t)row * D_ + col] = (_Float16)v;
      }
    }
  }
#pragma unroll
  for (int d = 1; d < 16; d <<= 1) {
#pragma unroll
    for (int j = 0; j < 4; ++j) ss[j] += __shfl_xor(ss[j], d, 64);
  }
  if (lr == 0) {
#pragma unroll
    for (int j = 0; j < 4; ++j) {
      int row = rowbase + w * 16 + lq * 4 + j;
      rnX[row] = 1.0f / fmaxf(sqrtf(ss[j]), 1e-12f);
    }
  }
}

// ---------------- kernel 8: LDS-free register GEMM + fused fixed-max logsumexp --------
// A (64 rows/block, 16/wave) in registers; B fragments streamed from L2-resident sHat.
// No __syncthreads in the main loop. Cosines <= 1 -> fixed max of 1 (no online max).
// Pad cols 1000..1023 have sHat rows == 0 -> v == 0 -> constant 24*e^-1 correction.
__global__ __launch_bounds__(256) void ace_kernel(const _Float16* __restrict__ xHat,
                                                  const _Float16* __restrict__ sHat,
                                                  const float* __restrict__ rnX,
                                                  const int* __restrict__ labels,
                                                  float* __restrict__ outACE,
                                                  double* __restrict__ acc_loss) {
  __shared__ float part[16];
  const int tid = threadIdx.x;
  const int w = tid >> 6, l = tid & 63, lr = l & 15, lq = l >> 4;
  const int rowbase = blockIdx.x * 64;
  const int arow = rowbase + w * 16 + lr;       // A-operand row for this lane

  // load A fragments (row arow, k = ks*32 + lq*8 .. +7), unnormalized
  f16x8 a[8];
  {
    const _Float16* ap = xHat + (size_t)arow * D_ + lq * 8;
#pragma unroll
    for (int ks = 0; ks < 8; ++ks) a[ks] = *(const f16x8*)(ap + ks * 32);
  }

  int lab[4]; float rx[4], ssum[4], num[4];
#pragma unroll
  for (int j = 0; j < 4; ++j) {
    int row = rowbase + w * 16 + lq * 4 + j;    // C-layout row for this lane
    lab[j] = labels[row];
    rx[j] = rnX[row];
    ssum[j] = 0.f; num[j] = 0.f;
  }

  const _Float16* bbase = sHat + (size_t)lr * D_ + lq * 8;
  float* const outrow = outACE + (size_t)(rowbase + w * 16 + lq * 4) * C_;

  for (int ch = 0; ch < 8; ++ch) {
    const int c0 = ch * 128;
    f32x4 acc[8];
#pragma unroll
    for (int t = 0; t < 8; ++t) acc[t] = (f32x4){0.f, 0.f, 0.f, 0.f};
#pragma unroll
    for (int ks = 0; ks < 8; ++ks) {
#pragma unroll
      for (int t = 0; t < 8; ++t) {
        f16x8 bf = *(const f16x8*)(bbase + (size_t)(c0 + t * 16) * D_ + ks * 32);
        acc[t] = __builtin_amdgcn_mfma_f32_16x16x32_f16(a[ks], bf, acc[t], 0, 0, 0);
      }
    }
#pragma unroll
    for (int t = 0; t < 8; ++t) {
      const int col = c0 + t * 16 + lr;
#pragma unroll
      for (int j = 0; j < 4; ++j) {
        float v = acc[t][j] * rx[j];
        if (col < C_) outrow[(size_t)j * C_ + col] = v;
        ssum[j] += __expf(v - 1.0f);
        num[j] = (col == lab[j]) ? v : num[j];
      }
    }
  }
#pragma unroll
  for (int d2 = 1; d2 < 16; d2 <<= 1) {
#pragma unroll
    for (int j = 0; j < 4; ++j) {
      ssum[j] += __shfl_xor(ssum[j], d2, 64);
      num[j]  += __shfl_xor(num[j], d2, 64);
    }
  }
  if (lr == 0) {
    const float padcorr = 24.0f * __expf(-1.0f);
    float contrib = 0.f;
#pragma unroll
    for (int j = 0; j < 4; ++j)
      contrib += num[j] - (1.0f + __logf(ssum[j] - padcorr));
    part[w * 4 + lq] = contrib;
  }
  __syncthreads();
  if (tid == 0) {
    float s = 0.f;
#pragma unroll
    for (int p2 = 0; p2 < 16; ++p2) s += part[p2];
    atomicAdd(acc_loss, (double)s);
  }
}

// ---------------- kernel 9: finalize loss ----------------
__global__ void fin_kernel(const double* a, float* out) {
  out[0] = (float)(-(*a) / (double)B_);
}

extern "C" void kernel_launch(void* const* d_in, const int* in_sizes, int n_in,
                              void* d_out, int out_size, void* d_ws, size_t ws_size,
                              hipStream_t stream) {
  const float* X      = (const float*)d_in[0];
  const int*   labels = (const int*)d_in[1];
  const float* S      = (const float*)d_in[2];
  const float* means  = (const float*)d_in[3];
  const float* bc     = (const float*)d_in[4];
  float* out = (float*)d_out;

  char* w = (char*)d_ws;
  double*    acc  = (double*)(w + 0);
  double*    C64  = (double*)(w + 256);          // 512 KB
  double*    Wcol = (double*)(w + 524544);       // 512 KB
  _Float16*  Wb   = (_Float16*)(w + 1048832);    // 128 KB
  _Float16*  WbT  = (_Float16*)(w + 1179904);    // 128 KB
  _Float16*  sHat = (_Float16*)(w + 1310976);    // 512 KB (1024 rows, pads zeroed)
  float*     rnX  = (float*)(w + 1835264);       // 256 KB
  _Float16*  xHat = (_Float16*)(w + 2097408);    // 32 MB
  float*     bcT  = (float*)(w + 2097408);       // aliases xHat (used before xform)

  transpose_kernel<<<64, 256, 0, stream>>>(bc, bcT, acc);
  cov_kernel<<<256, 256, 0, stream>>>(bc, bcT, C64);
  for (int p = 0; p < 4; ++p) {
    chol_panel<<<1, 256, 0, stream>>>(C64, p);
    int nt = 3 - p;
    if (nt > 0) chol_trail<<<nt * (nt + 1) / 2, 256, 0, stream>>>(C64, p);
  }
  inv_kernel<<<256, 256, 0, stream>>>(C64, Wcol);
  convert_kernel<<<256, 256, 0, stream>>>(Wcol, Wb, WbT);
  sig_kernel<<<1024, 256, 0, stream>>>(S, WbT, sHat);
  xform_kernel<<<1024, 256, 0, stream>>>(X, means, Wb, xHat, rnX);
  ace_kernel<<<1024, 256, 0, stream>>>(xHat, sHat, rnX, labels, out + 1, acc);
  fin_kernel<<<1, 1, 0, stream>>>(acc, out);
}

// Round 5
// 446.465 us; speedup vs baseline: 1.2616x; 1.2616x over previous
//
#include <hip/hip_runtime.h>
#include <hip/hip_bf16.h>
#include <math.h>

#define D_ 256
#define B_ 65536
#define C_ 1000

typedef _Float16 f16x8 __attribute__((ext_vector_type(8)));
typedef _Float16 f16x4 __attribute__((ext_vector_type(4)));
typedef float f32x4 __attribute__((ext_vector_type(4)));

// ---------------- kernel 0: transpose bc (256x256 f32) + zero loss acc ----------------
__global__ void transpose_kernel(const float* __restrict__ in, float* __restrict__ out,
                                 double* __restrict__ acc) {
  __shared__ float t[32][33];
  if (blockIdx.x == 0 && threadIdx.x == 0) *acc = 0.0;
  const int bx = blockIdx.x & 7, by = blockIdx.x >> 3;
  const int lx = threadIdx.x & 31, ly = threadIdx.x >> 5;  // 32 x 8
#pragma unroll
  for (int s = 0; s < 4; ++s) {
    int r = by * 32 + ly + s * 8;
    t[ly + s * 8][lx] = in[r * 256 + bx * 32 + lx];
  }
  __syncthreads();
#pragma unroll
  for (int s = 0; s < 4; ++s) {
    int r = bx * 32 + ly + s * 8;
    out[r * 256 + by * 32 + lx] = t[lx][ly + s * 8];
  }
}

// ---------------- kernel 1: cov = bc @ bc^T in fp64 (coalesced via bcT) ----------------
__global__ void cov_kernel(const float* __restrict__ bc, const float* __restrict__ bcT,
                           double* __restrict__ C64) {
  const int i = blockIdx.x, j = threadIdx.x;
  __shared__ float ri[D_];
  ri[j] = bc[i * D_ + j];
  __syncthreads();
  double s = 0.0;
#pragma unroll 8
  for (int k = 0; k < D_; ++k) s += (double)ri[k] * (double)bcT[k * D_ + j];
  C64[i * D_ + j] = s;
}

// ---------------- kernel 2a: factor panel p (64 cols), rows in registers ----------------
__global__ __launch_bounds__(256, 1) void chol_panel(double* __restrict__ A, int p) {
  const int j0 = p * 64;
  const int r = threadIdx.x;
  __shared__ double rowv[64];
  __shared__ double dinv;
  double pr[64];
  const bool act = (r >= j0);
  if (act) {
#pragma unroll
    for (int k = 0; k < 64; ++k) pr[k] = A[(size_t)r * D_ + j0 + k];
  }
#pragma unroll
  for (int j = 0; j < 64; ++j) {
    const int col = j0 + j;
    if (r == col) { double d = sqrt(pr[j]); pr[j] = d; dinv = 1.0 / d; }
    __syncthreads();
    if (r > col) {
      double lr = pr[j] * dinv;
      pr[j] = lr;
      if (r < j0 + 64) rowv[r - j0] = lr;
    }
    __syncthreads();
    if (r > col) {
      const double lr = pr[j];
#pragma unroll
      for (int k = j + 1; k < 64; ++k) pr[k] -= lr * rowv[k];
    }
  }
  if (act) {
    const int kmax = (r - j0 < 63) ? (r - j0) : 63;
#pragma unroll
    for (int k = 0; k < 64; ++k)
      if (k <= kmax) A[(size_t)r * D_ + j0 + k] = pr[k];
  }
}

// ---------------- kernel 2b: trailing update for panel p, one block per 64x64 tile ----
__global__ __launch_bounds__(256) void chol_trail(double* __restrict__ A, int p) {
  const int j0 = p * 64;
  const int t0 = j0 + 64;
  int b = blockIdx.x, I = 0;
  while (b >= I + 1) { b -= I + 1; ++I; }   // lower tile pair (I,J), J<=I
  const int J = b;
  const int r0 = t0 + I * 64, c0 = t0 + J * 64;
  __shared__ double LR[64][67];
  __shared__ double LC[64][67];
  const int tid = threadIdx.x;
  for (int e = tid; e < 64 * 64; e += 256) {
    int rr = e >> 6, cc = e & 63;
    LR[rr][cc] = A[(size_t)(r0 + rr) * D_ + j0 + cc];
    LC[rr][cc] = A[(size_t)(c0 + rr) * D_ + j0 + cc];
  }
  __syncthreads();
  const int tx = tid & 15, ty = tid >> 4;
  double acc[4][4];
#pragma unroll
  for (int i = 0; i < 4; ++i)
#pragma unroll
    for (int j = 0; j < 4; ++j) acc[i][j] = 0.0;
#pragma unroll 4
  for (int k = 0; k < 64; ++k) {
    double a_[4], b_[4];
#pragma unroll
    for (int i = 0; i < 4; ++i) a_[i] = LR[ty + 16 * i][k];
#pragma unroll
    for (int j = 0; j < 4; ++j) b_[j] = LC[tx + 16 * j][k];
#pragma unroll
    for (int i = 0; i < 4; ++i)
#pragma unroll
      for (int j = 0; j < 4; ++j) acc[i][j] += a_[i] * b_[j];
  }
#pragma unroll
  for (int i = 0; i < 4; ++i) {
    const int grow = r0 + ty + 16 * i;
#pragma unroll
    for (int j = 0; j < 4; ++j) {
      const int gcol = c0 + tx + 16 * j;
      A[(size_t)grow * D_ + gcol] -= acc[i][j];
    }
  }
}

// ---------------- kernel 3: W = L^-1 column c + direct f16 emit (convert folded in) ---
__global__ __launch_bounds__(256) void inv_kernel(const double* __restrict__ L,
                                                  _Float16* __restrict__ Wb,
                                                  _Float16* __restrict__ WbT) {
  const int c = blockIdx.x;
  const int tid = threadIdx.x;
  __shared__ double w[D_];
  __shared__ double rdi[D_];
  __shared__ double rhs[32];
  __shared__ double Ldd[32][33];
  w[tid] = 0.0;
  rdi[tid] = 1.0 / L[(size_t)tid * D_ + tid];
  __syncthreads();
  const int q0 = c >> 5;
  for (int q = q0; q < 8; ++q) {
    const int i0 = q * 32;
    const int ii = tid >> 3, s = tid & 7;
    const int i = i0 + ii;
    double part = 0.0;
    for (int k = c + s; k < i0; k += 8) part += L[(size_t)i * D_ + k] * w[k];
    part += __shfl_xor(part, 1, 64);
    part += __shfl_xor(part, 2, 64);
    part += __shfl_xor(part, 4, 64);
    if (s == 0) rhs[ii] = ((i == c) ? 1.0 : 0.0) - part;
    for (int e = tid; e < 32 * 32; e += 256) {
      int rr = e >> 5, cc = e & 31;
      Ldd[rr][cc] = L[(size_t)(i0 + rr) * D_ + i0 + cc];
    }
    __syncthreads();
    if (tid < 32) {
      double x = rhs[tid];
      double v = 0.0;
      for (int j = 0; j < 32; ++j) {
        double xj = __shfl(x, j, 64);
        double wj = xj * rdi[i0 + j];
        if (tid == j) v = wj;
        if (tid > j) x -= Ldd[tid][j] * wj;
      }
      w[i0 + tid] = v;
    }
    __syncthreads();
  }
  // w[] holds full column c of W = L^-1 (zeros above c). Emit f16 both layouts.
  _Float16 h = (_Float16)(float)w[tid];
  WbT[(size_t)c * D_ + tid] = h;   // WbT[k=c][i=tid] ... W[tid][c], coalesced
  Wb[(size_t)tid * D_ + c] = h;    // Wb[i=tid][k=c]
}

// ---------------- kernel 5: signatures, normalized, packed MFMA-fragment layout -------
// sHatP element layout: block (g,ks) of 512 elems at ((g*8+ks)*512); within it,
// chunk l (l=0..63) = 8 elems: col = g*16 + (l&15), k = ks*32 + (l>>4)*8 .. +7.
// In ace, lane l reads chunk l -> every B-load is one contiguous 1KB wave read.
__global__ void sig_kernel(const float* __restrict__ S, const _Float16* __restrict__ WbT,
                           _Float16* __restrict__ sHatP) {
  int c = blockIdx.x, i = threadIdx.x;
  const int g = c >> 4, lr = c & 15;
  const int ks = i >> 5, lq = (i >> 3) & 3, jj = i & 7;
  const size_t off = (size_t)(g * 8 + ks) * 512 + (size_t)(lq * 16 + lr) * 8 + jj;
  if (c >= C_) { sHatP[off] = (_Float16)0.0f; return; }  // pad classes exactly 0
  __shared__ float srow[D_];
  __shared__ float wred[4];
  srow[i] = S[c * D_ + i];
  __syncthreads();
  float t = 0.f;
  for (int k = 0; k < D_; ++k) t += (float)WbT[k * D_ + i] * srow[k];
  float ss = t * t;
#pragma unroll
  for (int d = 1; d < 64; d <<= 1) ss += __shfl_xor(ss, d, 64);
  if ((i & 63) == 0) wred[i >> 6] = ss;
  __syncthreads();
  float tot = wred[0] + wred[1] + wred[2] + wred[3];
  float rn = 1.0f / fmaxf(sqrtf(tot), 1e-12f);
  sHatP[off] = (_Float16)(t * rn);
}

// ---------------- kernel 6: xHat_un = (X - m) @ W^T (MFMA), rnX per row ----------------
__global__ __launch_bounds__(256) void xform_kernel(const float* __restrict__ X,
                                                    const float* __restrict__ means,
                                                    const _Float16* __restrict__ Wb,
                                                    _Float16* __restrict__ xHat,
                                                    float* __restrict__ rnX) {
  __shared__ __align__(16) _Float16 As[64 * D_];   // 32 KB, swizzled
  __shared__ __align__(16) _Float16 Bs[128 * D_];  // 64 KB, swizzled
  __shared__ float msh[D_];
  const int tid = threadIdx.x;
  const int rowbase = blockIdx.x * 64;
  msh[tid] = means[tid];
  __syncthreads();
  for (int s = 0; s < 16; ++s) {
    int c = s * 256 + tid;
    int r = c >> 6, q = c & 63;
    const float4 xv = *(const float4*)(X + (size_t)(rowbase + r) * D_ + q * 4);
    f16x4 hv;
    hv[0] = (_Float16)(xv.x - msh[q * 4 + 0]);
    hv[1] = (_Float16)(xv.y - msh[q * 4 + 1]);
    hv[2] = (_Float16)(xv.z - msh[q * 4 + 2]);
    hv[3] = (_Float16)(xv.w - msh[q * 4 + 3]);
    int byte = (q * 8) ^ ((r & 7) << 4);
    *(f16x4*)((char*)(As + r * D_) + byte) = hv;
  }
  const int w = tid >> 6, l = tid & 63, lr = l & 15, lq = l >> 4;
  float ss[4] = {0.f, 0.f, 0.f, 0.f};
  for (int ch = 0; ch < 2; ++ch) {
    __syncthreads();
    for (int s = 0; s < 16; ++s) {
      int c = s * 256 + tid;
      int r = c >> 5, q = c & 31;
      uint4 v = *(const uint4*)(Wb + (size_t)(ch * 128 + r) * D_ + q * 8);
      int byte = (q * 16) ^ ((r & 7) << 4);
      *(uint4*)((char*)(Bs + r * D_) + byte) = v;
    }
    __syncthreads();
    f32x4 acc[8];
#pragma unroll
    for (int t = 0; t < 8; ++t) acc[t] = (f32x4){0.f, 0.f, 0.f, 0.f};
#pragma unroll
    for (int ks = 0; ks < 8; ++ks) {
      int arow = w * 16 + lr;
      int abyte = (ks * 64 + lq * 16) ^ ((arow & 7) << 4);
      f16x8 af = *(const f16x8*)((char*)(As + arow * D_) + abyte);
#pragma unroll
      for (int t = 0; t < 8; ++t) {
        int brow = t * 16 + lr;
        int bbyte = (ks * 64 + lq * 16) ^ ((brow & 7) << 4);
        f16x8 bf = *(const f16x8*)((char*)(Bs + brow * D_) + bbyte);
        acc[t] = __builtin_amdgcn_mfma_f32_16x16x32_f16(af, bf, acc[t], 0, 0, 0);
      }
    }
#pragma unroll
    for (int t = 0; t < 8; ++t) {
      int col = ch * 128 + t * 16 + lr;
#pragma unroll
      for (int j = 0; j < 4; ++j) {
        int row = rowbase + w * 16 + lq * 4 + j;
        float v = acc[t][j];
        ss[j] += v * v;
        xHat[(size_t)row * D_ + col] = (_Float16)v;
      }
    }
  }
#pragma unroll
  for (int d = 1; d < 16; d <<= 1) {
#pragma unroll
    for (int j = 0; j < 4; ++j) ss[j] += __shfl_xor(ss[j], d, 64);
  }
  if (lr == 0) {
#pragma unroll
    for (int j = 0; j < 4; ++j) {
      int row = rowbase + w * 16 + lq * 4 + j;
      rnX[row] = 1.0f / fmaxf(sqrtf(ss[j]), 1e-12f);
    }
  }
}

// ---------------- kernel 8: LDS-free register GEMM, packed-B coalesced loads ----------
// A in registers; every B fragment load is a contiguous 1KB wave-wide read from the
// L2-resident packed sHatP. No barriers in the main loop. Fixed-max logsumexp (v<=1).
__global__ __launch_bounds__(256) void ace_kernel(const _Float16* __restrict__ xHat,
                                                  const _Float16* __restrict__ sHatP,
                                                  const float* __restrict__ rnX,
                                                  const int* __restrict__ labels,
                                                  float* __restrict__ outACE,
                                                  double* __restrict__ acc_loss) {
  __shared__ float part[16];
  const int tid = threadIdx.x;
  const int w = tid >> 6, l = tid & 63, lr = l & 15, lq = l >> 4;
  const int rowbase = blockIdx.x * 64;
  const int arow = rowbase + w * 16 + lr;       // A-operand row for this lane

  f16x8 a[8];
  {
    const _Float16* ap = xHat + (size_t)arow * D_ + lq * 8;
#pragma unroll
    for (int ks = 0; ks < 8; ++ks) a[ks] = *(const f16x8*)(ap + ks * 32);
  }

  int lab[4]; float rx[4], ssum[4], num[4];
#pragma unroll
  for (int j = 0; j < 4; ++j) {
    int row = rowbase + w * 16 + lq * 4 + j;    // C-layout row for this lane
    lab[j] = labels[row];
    rx[j] = rnX[row];
    ssum[j] = 0.f; num[j] = 0.f;
  }

  const _Float16* bl = sHatP + (size_t)l * 8;   // lane's chunk within each 1KB block
  float* const outrow = outACE + (size_t)(rowbase + w * 16 + lq * 4) * C_;

  for (int ch = 0; ch < 8; ++ch) {
    f32x4 acc[8];
#pragma unroll
    for (int t = 0; t < 8; ++t) acc[t] = (f32x4){0.f, 0.f, 0.f, 0.f};
#pragma unroll
    for (int ks = 0; ks < 8; ++ks) {
#pragma unroll
      for (int t = 0; t < 8; ++t) {
        f16x8 bf = *(const f16x8*)(bl + (size_t)((ch * 8 + t) * 8 + ks) * 512);
        acc[t] = __builtin_amdgcn_mfma_f32_16x16x32_f16(a[ks], bf, acc[t], 0, 0, 0);
      }
    }
#pragma unroll
    for (int t = 0; t < 8; ++t) {
      const int col = ch * 128 + t * 16 + lr;
#pragma unroll
      for (int j = 0; j < 4; ++j) {
        float v = acc[t][j] * rx[j];
        if (col < C_) outrow[(size_t)j * C_ + col] = v;
        ssum[j] += __expf(v - 1.0f);
        num[j] = (col == lab[j]) ? v : num[j];
      }
    }
  }
#pragma unroll
  for (int d2 = 1; d2 < 16; d2 <<= 1) {
#pragma unroll
    for (int j = 0; j < 4; ++j) {
      ssum[j] += __shfl_xor(ssum[j], d2, 64);
      num[j]  += __shfl_xor(num[j], d2, 64);
    }
  }
  if (lr == 0) {
    const float padcorr = 24.0f * __expf(-1.0f);
    float contrib = 0.f;
#pragma unroll
    for (int j = 0; j < 4; ++j)
      contrib += num[j] - (1.0f + __logf(ssum[j] - padcorr));
    part[w * 4 + lq] = contrib;
  }
  __syncthreads();
  if (tid == 0) {
    float s = 0.f;
#pragma unroll
    for (int p2 = 0; p2 < 16; ++p2) s += part[p2];
    atomicAdd(acc_loss, (double)s);
  }
}

// ---------------- kernel 9: finalize loss ----------------
__global__ void fin_kernel(const double* a, float* out) {
  out[0] = (float)(-(*a) / (double)B_);
}

extern "C" void kernel_launch(void* const* d_in, const int* in_sizes, int n_in,
                              void* d_out, int out_size, void* d_ws, size_t ws_size,
                              hipStream_t stream) {
  const float* X      = (const float*)d_in[0];
  const int*   labels = (const int*)d_in[1];
  const float* S      = (const float*)d_in[2];
  const float* means  = (const float*)d_in[3];
  const float* bc     = (const float*)d_in[4];
  float* out = (float*)d_out;

  char* w = (char*)d_ws;
  double*    acc   = (double*)(w + 0);
  double*    C64   = (double*)(w + 256);          // 512 KB
  _Float16*  Wb    = (_Float16*)(w + 524544);     // 128 KB
  _Float16*  WbT   = (_Float16*)(w + 655616);     // 128 KB
  _Float16*  sHatP = (_Float16*)(w + 786688);     // 512 KB packed (1024 classes)
  float*     rnX   = (float*)(w + 1310976);       // 256 KB
  _Float16*  xHat  = (_Float16*)(w + 1573120);    // 32 MB
  float*     bcT   = (float*)(w + 1573120);       // aliases xHat (used before xform)

  transpose_kernel<<<64, 256, 0, stream>>>(bc, bcT, acc);
  cov_kernel<<<256, 256, 0, stream>>>(bc, bcT, C64);
  for (int p = 0; p < 4; ++p) {
    chol_panel<<<1, 256, 0, stream>>>(C64, p);
    int nt = 3 - p;
    if (nt > 0) chol_trail<<<nt * (nt + 1) / 2, 256, 0, stream>>>(C64, p);
  }
  inv_kernel<<<256, 256, 0, stream>>>(C64, Wb, WbT);
  sig_kernel<<<1024, 256, 0, stream>>>(S, WbT, sHatP);
  xform_kernel<<<1024, 256, 0, stream>>>(X, means, Wb, xHat, rnX);
  ace_kernel<<<1024, 256, 0, stream>>>(xHat, sHatP, rnX, labels, out + 1, acc);
  fin_kernel<<<1, 1, 0, stream>>>(acc, out);
}